// Round 2
// baseline (13939.847 us; speedup 1.0000x reference)
//
#include <hip/hip_runtime.h>
#include <hip/hip_bf16.h>

typedef __hip_bfloat16 bf16;

// Problem constants
#define CB 2
#define CS 4096
#define CD 1024
#define CL 512
#define CST 64
#define CH 8
#define CT 640      // 2*ST + L
#define CDH 4096
#define NSEG 8
#define MCH 1024    // MLP M-chunk rows

__device__ __forceinline__ float tof(float x) { return x; }
__device__ __forceinline__ float tof(bf16 x) { return __bfloat162float(x); }
__device__ __forceinline__ void storev(float* p, float v) { *p = v; }
__device__ __forceinline__ void storev(bf16* p, float v) { *p = __float2bfloat16(v); }

// runtime-dtype input load: f32w!=0 -> buffer is float32, else bf16
__device__ __forceinline__ float ldin(const void* p, size_t i, int f32w) {
    if (f32w) return ((const float*)p)[i];
    return __bfloat162float(((const bf16*)p)[i]);
}

// ---------------------------------------------------------------------------
// Dtype sniffer: if x is an fp32 buffer, bf16-elements at even indices are the
// LOW mantissa halves of floats -> wild exponents. If x is a genuine bf16
// buffer they are N(0,1)-ish data. flag=1 -> inputs are fp32.
// ---------------------------------------------------------------------------
__global__ void sniff_kernel(const void* x, int* flag) {
    if (threadIdx.x == 0 && blockIdx.x == 0) {
        const bf16* hb = (const bf16*)x;
        int plaus = 0;
        for (int i = 0; i < 256; ++i) {
            float v = __bfloat162float(hb[2 * i]);
            float a = fabsf(v);
            if (v == 0.f || (a > 1e-4f && a < 100.f)) ++plaus;
        }
        flag[0] = (plaus < 128) ? 1 : 0;
    }
}

// ---------------------------------------------------------------------------
// Generic tiled GEMM: C[M,N] = A[M,K] (row-major, internal dtype TA) *
// Bw[K,N] (row-major, flagged input dtype). out_mode 0: row-major C.
// out_mode 1: head-major (b,h,t,k). act 1: exact GELU.
// blockIdx.z selects among 3 (B,C) pairs (QKV fuse).
// ---------------------------------------------------------------------------
template <typename TA, typename TC>
__global__ __launch_bounds__(256) void gemm_kernel(
    const TA* __restrict__ A,
    const void* __restrict__ B0, const void* __restrict__ B1, const void* __restrict__ B2,
    TC* __restrict__ C0, TC* __restrict__ C1, TC* __restrict__ C2,
    int M, int N, int K, const void* __restrict__ bias, int out_mode, int act,
    const int* __restrict__ flag)
{
    const int f32w = flag[0];
    const void* Bw = (blockIdx.z == 0) ? B0 : (blockIdx.z == 1 ? B1 : B2);
    TC* C = (blockIdx.z == 0) ? C0 : (blockIdx.z == 1 ? C1 : C2);

    __shared__ float As[16][65];
    __shared__ float Bs[16][65];

    int tid = threadIdx.x;
    int tx = tid & 15, ty = tid >> 4;
    int bm = blockIdx.x * 64, bn = blockIdx.y * 64;

    float acc[4][4] = {};

    for (int k0 = 0; k0 < K; k0 += 16) {
#pragma unroll
        for (int i = 0; i < 4; ++i) {
            int e = tid + i * 256;
            int r = e >> 4, c = e & 15;
            As[c][r] = tof(A[(size_t)(bm + r) * K + (k0 + c)]);
        }
#pragma unroll
        for (int i = 0; i < 4; ++i) {
            int e = tid + i * 256;
            int r = e >> 6, c = e & 63;
            Bs[r][c] = ldin(Bw, (size_t)(k0 + r) * N + (bn + c), f32w);
        }
        __syncthreads();
#pragma unroll
        for (int kk = 0; kk < 16; ++kk) {
            float av[4], bv[4];
#pragma unroll
            for (int i = 0; i < 4; ++i) av[i] = As[kk][ty * 4 + i];
#pragma unroll
            for (int j = 0; j < 4; ++j) bv[j] = Bs[kk][tx * 4 + j];
#pragma unroll
            for (int i = 0; i < 4; ++i)
#pragma unroll
                for (int j = 0; j < 4; ++j) acc[i][j] += av[i] * bv[j];
        }
        __syncthreads();
    }

#pragma unroll
    for (int i = 0; i < 4; ++i) {
        int r = bm + ty * 4 + i;
#pragma unroll
        for (int j = 0; j < 4; ++j) {
            int c = bn + tx * 4 + j;
            float v = acc[i][j];
            if (bias) v += ldin(bias, c, f32w);
            if (act == 1) v = 0.5f * v * (1.0f + erff(v * 0.70710678118654752f));
            size_t idx;
            if (out_mode == 0) {
                idx = (size_t)r * N + c;
            } else {
                int b = r / CT, t = r % CT, hh = c >> 6, k2 = c & 63;
                idx = ((size_t)(b * CH + hh) * CT + t) * 64 + k2;
            }
            storev(C + idx, v);
        }
    }
}

// ---------------------------------------------------------------------------
// Causal attention, one wave per (b, h, t) query row. lane = dim (64).
// q,k,v: [b][h][t][64] fp32. Output strides passed.
// ---------------------------------------------------------------------------
__global__ __launch_bounds__(64) void attn_kernel(
    const float* __restrict__ q, const float* __restrict__ k, const float* __restrict__ v,
    float* __restrict__ o, int ob, int oh, int ot)
{
    int t = blockIdx.x, hh = blockIdx.y, b = blockIdx.z;
    int lane = threadIdx.x;
    size_t base = (size_t)(b * CH + hh) * CT * 64;
    float qd = q[base + (size_t)t * 64 + lane];

    float m = -1e30f, l = 0.f, acc = 0.f;
    for (int j = 0; j <= t; ++j) {
        float prod = qd * k[base + (size_t)j * 64 + lane];
#pragma unroll
        for (int off = 32; off; off >>= 1) prod += __shfl_xor(prod, off);
        float s = prod * 0.125f;  // 1/sqrt(64)
        float mn = fmaxf(m, s);
        float corr = __expf(m - mn);
        float p = __expf(s - mn);
        l = l * corr + p;
        acc = acc * corr + p * v[base + (size_t)j * 64 + lane];
        m = mn;
    }
    o[(size_t)b * ob + (size_t)hh * oh + (size_t)t * ot + lane] = acc / l;
}

// ---------------------------------------------------------------------------
// Level-1 projections: q1/k1/v1 = o0 @ Wq1/Wk1/Wv1 (per-head 64x64) + RoPE
// on q1,k1. One wave per (b,h,t).
// ---------------------------------------------------------------------------
__global__ __launch_bounds__(64) void proj1_kernel(
    const float* __restrict__ o0,
    const void* __restrict__ Wq1, const void* __restrict__ Wk1, const void* __restrict__ Wv1,
    float* __restrict__ q1, float* __restrict__ k1, float* __restrict__ v1,
    const int* __restrict__ flag)
{
    const int f32w = flag[0];
    int t = blockIdx.x, hh = blockIdx.y, b = blockIdx.z;
    int lane = threadIdx.x;
    __shared__ float os[64];
    size_t rowoff = ((size_t)(b * CH + hh) * CT + t) * 64;
    os[lane] = o0[rowoff + lane];
    __syncthreads();

    size_t wbase = (size_t)hh * 64 * 64;
    float aq = 0.f, ak = 0.f, av = 0.f;
#pragma unroll 8
    for (int vv = 0; vv < 64; ++vv) {
        float ov = os[vv];
        aq += ov * ldin(Wq1, wbase + vv * 64 + lane, f32w);
        ak += ov * ldin(Wk1, wbase + vv * 64 + lane, f32w);
        av += ov * ldin(Wv1, wbase + vv * 64 + lane, f32w);
    }
    // RoPE (interleaved pairs) on aq, ak
    int i = lane >> 1;
    float inv = powf(10000.f, -(float)(2 * i) / 64.f);
    float ang = (float)t * inv;
    float sn, cs;
    sincosf(ang, &sn, &cs);
    float oq = __shfl_xor(aq, 1);
    float okk = __shfl_xor(ak, 1);
    float rq, rk;
    if (lane & 1) { rq = oq * sn + aq * cs; rk = okk * sn + ak * cs; }
    else          { rq = aq * cs - oq * sn; rk = ak * cs - okk * sn; }
    q1[rowoff + lane] = rq;
    k1[rowoff + lane] = rk;
    v1[rowoff + lane] = av;
}

// RoPE over q0 and k0: [B][H][T][64], thread per (bh,t,pair)
__global__ __launch_bounds__(256) void rope_qk_kernel(float* __restrict__ q, float* __restrict__ k)
{
    int idx = blockIdx.x * 256 + threadIdx.x;  // B*H*T*32
    int i = idx & 31;
    int t = (idx >> 5) % CT;
    int bh = idx / (32 * CT);
    float inv = powf(10000.f, -(float)(2 * i) / 64.f);
    float ang = (float)t * inv;
    float sn, cs;
    sincosf(ang, &sn, &cs);
    size_t p = ((size_t)bh * CT + t) * 64 + 2 * i;
    float x1 = q[p], x2 = q[p + 1];
    q[p] = x1 * cs - x2 * sn;
    q[p + 1] = x1 * sn + x2 * cs;
    x1 = k[p]; x2 = k[p + 1];
    k[p] = x1 * cs - x2 * sn;
    k[p + 1] = x1 * sn + x2 * cs;
}

// toks = concat([state, x_seg, state]) along t
__global__ __launch_bounds__(256) void build_toks_kernel(
    const void* __restrict__ x, const float* __restrict__ state, float* __restrict__ toks,
    int seg, const int* __restrict__ flag)
{
    const int f32w = flag[0];
    int idx = blockIdx.x * 256 + threadIdx.x;  // B*T*D
    int d = idx & (CD - 1);
    int t = (idx >> 10) % CT;
    int b = idx / (CT * CD);
    float v;
    if (t < CST) v = state[(b * CST + t) * CD + d];
    else if (t < CST + CL) v = ldin(x, ((size_t)b * CS + seg * CL + (t - CST)) * CD + d, f32w);
    else v = state[(b * CST + (t - CST - CL)) * CD + d];
    toks[idx] = v;
}

// split seg_out: middle L tokens -> a, last ST tokens -> state
__global__ __launch_bounds__(256) void seg_epi_kernel(
    const float* __restrict__ seg_out, float* __restrict__ a, float* __restrict__ state, int seg)
{
    int idx = blockIdx.x * 256 + threadIdx.x;  // B*(T-ST)*D
    int d = idx & (CD - 1);
    int tt = (idx >> 10) % (CT - CST);
    int b = idx / ((CT - CST) * CD);
    float v = seg_out[((size_t)b * CT + (tt + CST)) * CD + d];
    if (tt < CL) a[((size_t)b * CS + seg * CL + tt) * CD + d] = v;
    else state[(b * CST + (tt - CL)) * CD + d] = v;
}

__global__ __launch_bounds__(256) void init_state_kernel(
    const void* __restrict__ s0, float* __restrict__ state, const int* __restrict__ flag)
{
    const int f32w = flag[0];
    int idx = blockIdx.x * 256 + threadIdx.x;  // B*ST*D
    state[idx] = ldin(s0, idx % (CST * CD), f32w);
}

// LayerNorm(ra + x) * g + b.
// out_ext=0: write bf16 to outp (internal h). out_ext=1: write flagged dtype.
__global__ __launch_bounds__(256) void ln_kernel(
    const float* __restrict__ ra, const void* __restrict__ x,
    const void* __restrict__ g, const void* __restrict__ bb,
    void* __restrict__ outp, int out_ext, const int* __restrict__ flag)
{
    const int f32w = flag[0];
    int row = blockIdx.x;
    int tid = threadIdx.x;
    __shared__ float buf[CD];
    __shared__ float red[4];

    float s = 0.f;
    for (int c = tid; c < CD; c += 256) {
        float v = ra[(size_t)row * CD + c] + ldin(x, (size_t)row * CD + c, f32w);
        buf[c] = v;
        s += v;
    }
#pragma unroll
    for (int off = 32; off; off >>= 1) s += __shfl_xor(s, off);
    if ((tid & 63) == 0) red[tid >> 6] = s;
    __syncthreads();
    float mu = (red[0] + red[1] + red[2] + red[3]) * (1.f / CD);
    __syncthreads();

    float vs = 0.f;
    for (int c = tid; c < CD; c += 256) {
        float d0 = buf[c] - mu;
        vs += d0 * d0;
    }
#pragma unroll
    for (int off = 32; off; off >>= 1) vs += __shfl_xor(vs, off);
    if ((tid & 63) == 0) red[tid >> 6] = vs;
    __syncthreads();
    float var = (red[0] + red[1] + red[2] + red[3]) * (1.f / CD);
    float rs = rsqrtf(var + 1e-5f);

    for (int c = tid; c < CD; c += 256) {
        float y = (buf[c] - mu) * rs * ldin(g, c, f32w) + ldin(bb, c, f32w);
        size_t idx = (size_t)row * CD + c;
        if (!out_ext) {
            ((bf16*)outp)[idx] = __float2bfloat16(y);
        } else if (f32w) {
            ((float*)outp)[idx] = y;
        } else {
            ((bf16*)outp)[idx] = __float2bfloat16(y);
        }
    }
}

extern "C" void kernel_launch(void* const* d_in, const int* in_sizes, int n_in,
                              void* d_out, int out_size, void* d_ws, size_t ws_size,
                              hipStream_t stream)
{
    const void* x      = d_in[0];
    const void* s0     = d_in[1];
    const void* Wq0    = d_in[2];
    const void* Wk0    = d_in[3];
    const void* Wv0    = d_in[4];
    const void* Wq1    = d_in[5];
    const void* Wk1    = d_in[6];
    const void* Wv1    = d_in[7];
    const void* Wo     = d_in[8];
    const void* bo     = d_in[9];
    const void* g_attn = d_in[10];
    const void* b_attn = d_in[11];
    const void* W1     = d_in[12];
    const void* b1     = d_in[13];
    const void* W2     = d_in[14];
    const void* b2     = d_in[15];
    const void* g_mlp  = d_in[16];
    const void* b_mlp  = d_in[17];

    // workspace carve-up: [flag:16B][fp32 arrays][bf16 arrays]  ~91 MB total
    int* flag = (int*)d_ws;
    float* f = (float*)((char*)d_ws + 16);
    float* toks = f;    f += (size_t)CB * CT * CD;        // 1,310,720
    float* q0 = f;      f += (size_t)CB * CH * CT * 64;   // 655,360
    float* k0 = f;      f += (size_t)CB * CH * CT * 64;
    float* v0 = f;      f += (size_t)CB * CH * CT * 64;
    float* o0 = f;      f += (size_t)CB * CH * CT * 64;
    float* q1 = f;      f += (size_t)CB * CH * CT * 64;
    float* k1 = f;      f += (size_t)CB * CH * CT * 64;
    float* v1 = f;      f += (size_t)CB * CH * CT * 64;
    float* o1t = f;     f += (size_t)CB * CT * (CH * 64); // [b][t][h*64+v]
    float* seg_out = f; f += (size_t)CB * CT * CD;
    float* state = f;   f += (size_t)CB * CST * CD;
    float* a = f;       f += (size_t)CB * CS * CD;        // attn out; reused as MLP out
    bf16* h = (bf16*)f;                                   // LN1 output [B*S, D] bf16
    bf16* g1 = h + (size_t)CB * CS * CD;                  // MLP mid chunk [MCH, DH] bf16

    sniff_kernel<<<1, 64, 0, stream>>>(x, flag);
    init_state_kernel<<<(CB * CST * CD) / 256, 256, 0, stream>>>(s0, state, flag);

    for (int seg = 0; seg < NSEG; ++seg) {
        build_toks_kernel<<<(CB * CT * CD) / 256, 256, 0, stream>>>(x, state, toks, seg, flag);
        // q0,k0,v0 = toks @ {Wq0,Wk0,Wv0}  (M=1280, N=512, K=1024), head-major out
        gemm_kernel<float, float><<<dim3(20, 8, 3), 256, 0, stream>>>(
            toks, Wq0, Wk0, Wv0, q0, k0, v0, CB * CT, CH * 64, CD, nullptr, 1, 0, flag);
        rope_qk_kernel<<<(CB * CH * CT * 32) / 256, 256, 0, stream>>>(q0, k0);
        attn_kernel<<<dim3(CT, CH, CB), 64, 0, stream>>>(
            q0, k0, v0, o0, CH * CT * 64, CT * 64, 64);
        proj1_kernel<<<dim3(CT, CH, CB), 64, 0, stream>>>(o0, Wq1, Wk1, Wv1, q1, k1, v1, flag);
        attn_kernel<<<dim3(CT, CH, CB), 64, 0, stream>>>(
            q1, k1, v1, o1t, CT * (CH * 64), 64, CH * 64);
        // seg_out = o1t @ Wo + bo  (M=1280, N=1024, K=512)
        gemm_kernel<float, float><<<dim3(20, 16, 1), 256, 0, stream>>>(
            o1t, Wo, Wo, Wo, seg_out, seg_out, seg_out, CB * CT, CD, CH * 64, bo, 0, 0, flag);
        seg_epi_kernel<<<(CB * (CT - CST) * CD) / 256, 256, 0, stream>>>(seg_out, a, state, seg);
    }

    // h = LN(a + x) -> bf16 internal
    ln_kernel<<<CB * CS, 256, 0, stream>>>(a, x, g_attn, b_attn, h, 0, flag);
    // MLP in M-chunks of 1024 rows: g1 = gelu(h_c @ W1 + b1); m_c = g1 @ W2 + b2
    for (int c = 0; c < (CB * CS) / MCH; ++c) {
        gemm_kernel<bf16, bf16><<<dim3(MCH / 64, CDH / 64, 1), 256, 0, stream>>>(
            h + (size_t)c * MCH * CD, W1, W1, W1, g1, g1, g1,
            MCH, CDH, CD, b1, 0, 1, flag);
        gemm_kernel<bf16, float><<<dim3(MCH / 64, CD / 64, 1), 256, 0, stream>>>(
            g1, W2, W2, W2, a + (size_t)c * MCH * CD, a, a,
            MCH, CD, CDH, b2, 0, 0, flag);
    }
    // out = LN(m + x) -> flagged external dtype
    ln_kernel<<<CB * CS, 256, 0, stream>>>(a, x, g_mlp, b_mlp, d_out, 1, flag);
}